// Round 1
// baseline (2664.756 us; speedup 1.0000x reference)
//
#include <hip/hip_runtime.h>
#include <math.h>

#define BATCH 2
#define TSEQ 1024
#define DIM 1024
#define NLAYER 12
#define EXPF_ 4
#define EDIM (EXPF_*DIM)      // 4096
#define BT (BATCH*TSEQ)       // 2048
#define EPS_LN 1e-5f

typedef __attribute__((ext_vector_type(4))) float  f32x4;
typedef __attribute__((ext_vector_type(8))) __bf16 bf16x8;
typedef __attribute__((ext_vector_type(4))) __bf16 bf16x4;
typedef __attribute__((ext_vector_type(2))) __bf16 bf16x2;

// ---------------------------------------------------------------- scores ---
// score[l',bt] = ( rs * (sum v*g*q - mu*sum g*q) + sum b*q ) * 1/sqrt(D)
// One wave per (l',bt) row.
__global__ void scores_kernel(const float* __restrict__ hist,
                              const float* __restrict__ q,
                              const float* __restrict__ g,
                              const float* __restrict__ bvec,
                              float* __restrict__ scores,
                              int nrows)
{
    int wid = blockIdx.x * (blockDim.x >> 6) + (threadIdx.x >> 6);
    if (wid >= nrows) return;
    int lane = threadIdx.x & 63;
    int lp = wid / BT;
    int bt = wid - lp * BT;
    const float* v = hist + (size_t)lp * BT * DIM + (size_t)bt * DIM;

    float s1 = 0.f, s2 = 0.f, sq = 0.f, sg = 0.f, sb = 0.f;
#pragma unroll
    for (int i = 0; i < 4; i++) {
        int d = i * 256 + lane * 4;
        f32x4 v4 = *(const f32x4*)(v + d);
        f32x4 g4 = *(const f32x4*)(g + d);
        f32x4 q4 = *(const f32x4*)(q + d);
        f32x4 b4 = *(const f32x4*)(bvec + d);
#pragma unroll
        for (int c = 0; c < 4; c++) {
            float vv = v4[c];
            float gq = g4[c] * q4[c];
            s1 += vv; s2 += vv * vv; sq += vv * gq; sg += gq; sb += b4[c] * q4[c];
        }
    }
#pragma unroll
    for (int off = 32; off; off >>= 1) {
        s1 += __shfl_xor(s1, off);
        s2 += __shfl_xor(s2, off);
        sq += __shfl_xor(sq, off);
        sg += __shfl_xor(sg, off);
        sb += __shfl_xor(sb, off);
    }
    if (lane == 0) {
        float mu = s1 * (1.0f / DIM);
        float var = s2 * (1.0f / DIM) - mu * mu;
        float rs = rsqrtf(var + EPS_LN);
        scores[wid] = (rs * (sq - mu * sg) + sb) * (1.0f / 32.0f);
    }
}

// --------------------------------------------------------------- softmax ---
__global__ void softmax_kernel(float* __restrict__ scores, int nl)
{
    int bt = blockIdx.x * blockDim.x + threadIdx.x;
    if (bt >= BT) return;
    float s[NLAYER + 1];
    float mx = -1e30f;
    for (int i = 0; i < nl; i++) { s[i] = scores[i * BT + bt]; mx = fmaxf(mx, s[i]); }
    float sum = 0.f;
    for (int i = 0; i < nl; i++) { s[i] = expf(s[i] - mx); sum += s[i]; }
    float inv = 1.0f / sum;
    for (int i = 0; i < nl; i++) scores[i * BT + bt] = s[i] * inv;
}

// ------------------------------------------------- residual + LN(h)->u -----
// One block per bt row: resid = sum alpha*V ; u = LN(h)*g+b (bf16).
__global__ void mix_ln_kernel(const float* __restrict__ hist,
                              const float* __restrict__ alpha,
                              const float* __restrict__ g,
                              const float* __restrict__ bvec,
                              float* __restrict__ resid,
                              __bf16* __restrict__ u,
                              int nl)
{
    __shared__ float sal[NLAYER + 1];
    __shared__ float red1[4], red2[4];
    int bt = blockIdx.x;
    int tid = threadIdx.x;
    if (tid < nl) sal[tid] = alpha[tid * BT + bt];
    __syncthreads();

    int d = tid * 4;
    f32x4 r; r[0] = 0.f; r[1] = 0.f; r[2] = 0.f; r[3] = 0.f;
    f32x4 h4;
    for (int lp = 0; lp < nl; lp++) {
        f32x4 v4 = *(const f32x4*)(hist + (size_t)lp * BT * DIM + (size_t)bt * DIM + d);
        float a = sal[lp];
        r[0] += a * v4[0]; r[1] += a * v4[1]; r[2] += a * v4[2]; r[3] += a * v4[3];
        h4 = v4;                       // last iteration (lp == nl-1) is h
    }
    *(f32x4*)(resid + (size_t)bt * DIM + d) = r;

    float s1 = h4[0] + h4[1] + h4[2] + h4[3];
    float s2 = h4[0]*h4[0] + h4[1]*h4[1] + h4[2]*h4[2] + h4[3]*h4[3];
#pragma unroll
    for (int off = 32; off; off >>= 1) {
        s1 += __shfl_xor(s1, off);
        s2 += __shfl_xor(s2, off);
    }
    int w = tid >> 6, lane = tid & 63;
    if (lane == 0) { red1[w] = s1; red2[w] = s2; }
    __syncthreads();
    s1 = red1[0] + red1[1] + red1[2] + red1[3];
    s2 = red2[0] + red2[1] + red2[2] + red2[3];
    float mu = s1 * (1.0f / DIM);
    float rs = rsqrtf(s2 * (1.0f / DIM) - mu * mu + EPS_LN);

    f32x4 g4 = *(const f32x4*)(g + d);
    f32x4 b4 = *(const f32x4*)(bvec + d);
    bf16x4 uo;
#pragma unroll
    for (int c = 0; c < 4; c++) uo[c] = (__bf16)((h4[c] - mu) * rs * g4[c] + b4[c]);
    *(bf16x4*)(u + (size_t)bt * DIM + d) = uo;
}

// ------------------------------------------------------------------ GEMM ---
// C = A(bf16, MxK) * B(f32 staged->bf16, KxN), 128x128 tile, 4 waves, BK=32.
// EPI==0: out = bf16 gelu(acc + bias)     (-> hmid)
// EPI==1: out = f32  acc + bias + resid   (-> next h)
#define BM 128
#define BN 128
#define BK 32
#define PADK 40

template <int EPI>
__global__ __launch_bounds__(256)
void gemm_kernel(const __bf16* __restrict__ A,
                 const float* __restrict__ Bsrc,
                 const float* __restrict__ bias,
                 const float* __restrict__ resid,
                 void* __restrict__ outp,
                 int M, int N, int K)
{
    __shared__ __bf16 Abuf[BM * PADK];
    __shared__ __bf16 Bbuf[BN * PADK];

    int m0 = blockIdx.y * BM;
    int n0 = blockIdx.x * BN;
    int tid = threadIdx.x;
    int lane = tid & 63;
    int w = tid >> 6;
    int wr = w >> 1, wc = w & 1;

    f32x4 acc[4][4];
#pragma unroll
    for (int i = 0; i < 4; i++)
#pragma unroll
        for (int j = 0; j < 4; j++) { acc[i][j][0]=0.f; acc[i][j][1]=0.f; acc[i][j][2]=0.f; acc[i][j][3]=0.f; }

    // A staging: thread -> (row ar, 16-elem half ak)
    int ar = tid >> 1;
    int ak = (tid & 1) << 4;
    int asw = ((ar >> 3) & 3) << 3;
    // B staging: thread -> (k-pair kp2, 8-wide n-group nb)
    int kp2 = (tid >> 4) << 1;
    int nb  = (tid & 15) << 3;
    int bsw = ((nb >> 3) & 3) << 3;     // (row>>3)&3 is constant over the thread's 8 rows

    int lr = lane & 15;
    int lk = (lane >> 4) << 3;

    for (int kt = 0; kt < K; kt += BK) {
        // ---- stage A (bf16 copy) ----
        const __bf16* ag = A + (size_t)(m0 + ar) * K + kt + ak;
        uint4 av0 = *(const uint4*)(ag);
        uint4 av1 = *(const uint4*)(ag + 8);
        *(uint4*)(&Abuf[ar * PADK + (ak ^ asw)]) = av0;
        *(uint4*)(&Abuf[ar * PADK + ((ak + 8) ^ asw)]) = av1;
        // ---- stage B (f32 -> bf16, transposed to n-major) ----
        const float* bg0 = Bsrc + (size_t)(kt + kp2) * N + n0 + nb;
        const float* bg1 = bg0 + N;
        f32x4 f0a = *(const f32x4*)(bg0);
        f32x4 f0b = *(const f32x4*)(bg0 + 4);
        f32x4 f1a = *(const f32x4*)(bg1);
        f32x4 f1b = *(const f32x4*)(bg1 + 4);
#pragma unroll
        for (int c = 0; c < 4; c++) {
            bf16x2 p; p[0] = (__bf16)f0a[c]; p[1] = (__bf16)f1a[c];
            *(bf16x2*)(&Bbuf[(nb + c) * PADK + (kp2 ^ bsw)]) = p;
        }
#pragma unroll
        for (int c = 0; c < 4; c++) {
            bf16x2 p; p[0] = (__bf16)f0b[c]; p[1] = (__bf16)f1b[c];
            *(bf16x2*)(&Bbuf[(nb + 4 + c) * PADK + (kp2 ^ bsw)]) = p;
        }
        __syncthreads();

        // ---- compute ----
        bf16x8 af[4], bf[4];
#pragma unroll
        for (int i = 0; i < 4; i++) {
            int rowa = wr * 64 + i * 16 + lr;
            af[i] = *(const bf16x8*)(&Abuf[rowa * PADK + (lk ^ (((rowa >> 3) & 3) << 3))]);
        }
#pragma unroll
        for (int j = 0; j < 4; j++) {
            int rowb = wc * 64 + j * 16 + lr;
            bf[j] = *(const bf16x8*)(&Bbuf[rowb * PADK + (lk ^ (((rowb >> 3) & 3) << 3))]);
        }
#pragma unroll
        for (int i = 0; i < 4; i++)
#pragma unroll
            for (int j = 0; j < 4; j++)
                acc[i][j] = __builtin_amdgcn_mfma_f32_16x16x32_bf16(af[i], bf[j], acc[i][j], 0, 0, 0);
        __syncthreads();
    }

    // ---- epilogue ----
    int lrow = (lane >> 4) << 2;
#pragma unroll
    for (int i = 0; i < 4; i++) {
#pragma unroll
        for (int j = 0; j < 4; j++) {
            int colg = n0 + wc * 64 + j * 16 + lr;
            float bcol = bias[colg];
#pragma unroll
            for (int r = 0; r < 4; r++) {
                int rowg = m0 + wr * 64 + i * 16 + lrow + r;
                float val = acc[i][j][r] + bcol;
                if (EPI == 0) {
                    float ge = 0.5f * val * (1.0f + erff(val * 0.70710678118654752f));
                    ((__bf16*)outp)[(size_t)rowg * N + colg] = (__bf16)ge;
                } else {
                    ((float*)outp)[(size_t)rowg * N + colg] = val + resid[(size_t)rowg * N + colg];
                }
            }
        }
    }
}

// ---------------------------------------------------------------- launch ---
extern "C" void kernel_launch(void* const* d_in, const int* in_sizes, int n_in,
                              void* d_out, int out_size, void* d_ws, size_t ws_size,
                              hipStream_t stream)
{
    const float* x   = (const float*)d_in[0];
    const float* q   = (const float*)d_in[1];
    const float* kng = (const float*)d_in[2];
    const float* knb = (const float*)d_in[3];
    const float* lng = (const float*)d_in[4];
    const float* lnb = (const float*)d_in[5];
    const float* W1  = (const float*)d_in[6];
    const float* b1  = (const float*)d_in[7];
    const float* W2  = (const float*)d_in[8];
    const float* b2  = (const float*)d_in[9];

    char* ws = (char*)d_ws;
    const size_t slot = (size_t)BT * DIM;               // elements per history slot
    float*  hist   = (float*)(ws);                      // 13 * 8 MB
    float*  resid  = (float*)(ws + 109051904);          // 8 MB
    float*  scores = (float*)(ws + 117440512);          // 13*2048*4
    __bf16* ubuf   = (__bf16*)(ws + 117547008);         // 4 MB
    __bf16* hmid   = (__bf16*)(ws + 121741312);         // 16 MB

    hipMemcpyAsync(hist, x, slot * sizeof(float), hipMemcpyDeviceToDevice, stream);

    for (int l = 0; l < NLAYER; l++) {
        int nl = l + 1;
        int nrows = nl * BT;
        scores_kernel<<<dim3((nrows + 3) / 4), 256, 0, stream>>>(
            hist, q + (size_t)l * DIM, kng + (size_t)l * DIM, knb + (size_t)l * DIM,
            scores, nrows);
        softmax_kernel<<<dim3(BT / 256), 256, 0, stream>>>(scores, nl);
        mix_ln_kernel<<<dim3(BT), 256, 0, stream>>>(
            hist, scores, lng + (size_t)l * DIM, lnb + (size_t)l * DIM,
            resid, ubuf, nl);
        gemm_kernel<0><<<dim3(EDIM / BN, BT / BM), 256, 0, stream>>>(
            ubuf, W1 + (size_t)l * DIM * EDIM, b1 + (size_t)l * EDIM,
            nullptr, (void*)hmid, BT, EDIM, DIM);
        gemm_kernel<1><<<dim3(DIM / BN, BT / BM), 256, 0, stream>>>(
            hmid, W2 + (size_t)l * EDIM * DIM, b2 + (size_t)l * DIM,
            resid, (void*)(hist + (size_t)(l + 1) * slot), BT, DIM, EDIM);
    }

    hipMemcpyAsync(d_out, hist + (size_t)NLAYER * slot, slot * sizeof(float),
                   hipMemcpyDeviceToDevice, stream);
}

// Round 2
// 1125.051 us; speedup vs baseline: 2.3686x; 2.3686x over previous
//
#include <hip/hip_runtime.h>
#include <math.h>

#define BATCH 2
#define TSEQ 1024
#define DIM 1024
#define NLAYER 12
#define EDIM 4096
#define BT 2048
#define EPS_LN 1e-5f

typedef __attribute__((ext_vector_type(4))) float  f32x4;
typedef __attribute__((ext_vector_type(8))) __bf16 bf16x8;
typedef __attribute__((ext_vector_type(4))) __bf16 bf16x4;

__device__ __forceinline__ void gl_lds16(const void* gptr, void* lptr) {
    __builtin_amdgcn_global_load_lds(
        (const __attribute__((address_space(1))) void*)gptr,
        (__attribute__((address_space(3))) void*)lptr,
        16, 0, 0);
}

// ---------------------------------------------------------------- scores ---
// score[l',bt] = ( rs * (sum v*g*q - mu*sum g*q) + sum b*q ) / sqrt(D)
__global__ void scores_kernel(const float* __restrict__ hist,
                              const float* __restrict__ q,
                              const float* __restrict__ g,
                              const float* __restrict__ bvec,
                              float* __restrict__ scores,
                              int nrows)
{
    int wid = blockIdx.x * (blockDim.x >> 6) + (threadIdx.x >> 6);
    if (wid >= nrows) return;
    int lane = threadIdx.x & 63;
    int lp = wid / BT;
    int bt = wid - lp * BT;
    const float* v = hist + (size_t)lp * BT * DIM + (size_t)bt * DIM;

    float s1 = 0.f, s2 = 0.f, sq = 0.f, sg = 0.f, sb = 0.f;
#pragma unroll
    for (int i = 0; i < 4; i++) {
        int d = i * 256 + lane * 4;
        f32x4 v4 = *(const f32x4*)(v + d);
        f32x4 g4 = *(const f32x4*)(g + d);
        f32x4 q4 = *(const f32x4*)(q + d);
        f32x4 b4 = *(const f32x4*)(bvec + d);
#pragma unroll
        for (int c = 0; c < 4; c++) {
            float vv = v4[c];
            float gq = g4[c] * q4[c];
            s1 += vv; s2 += vv * vv; sq += vv * gq; sg += gq; sb += b4[c] * q4[c];
        }
    }
#pragma unroll
    for (int off = 32; off; off >>= 1) {
        s1 += __shfl_xor(s1, off);
        s2 += __shfl_xor(s2, off);
        sq += __shfl_xor(sq, off);
        sg += __shfl_xor(sg, off);
        sb += __shfl_xor(sb, off);
    }
    if (lane == 0) {
        float mu = s1 * (1.0f / DIM);
        float var = s2 * (1.0f / DIM) - mu * mu;
        float rs = rsqrtf(var + EPS_LN);
        scores[wid] = (rs * (sq - mu * sg) + sb) * (1.0f / 32.0f);
    }
}

// ------------------------------- softmax + residual mix + LN(h) -> u -------
// One block per bt row. Writes hnext = resid + b2 (f32) and u = LN(h) (bf16).
__global__ void mix_ln_kernel(const float* __restrict__ hist,
                              const float* __restrict__ scores,
                              const float* __restrict__ g,
                              const float* __restrict__ bvec,
                              const float* __restrict__ b2,
                              float* __restrict__ hnext,
                              __bf16* __restrict__ u,
                              int nl)
{
    __shared__ float red1[4], red2[4];
    int bt = blockIdx.x;
    int tid = threadIdx.x;

    // in-register softmax over the (<=12) history scores (broadcast loads)
    float sc[NLAYER];
    float mx = -1e30f;
#pragma unroll
    for (int i = 0; i < NLAYER; i++) {
        sc[i] = (i < nl) ? scores[i * BT + bt] : -1e30f;
        mx = fmaxf(mx, sc[i]);
    }
    float ssum = 0.f;
#pragma unroll
    for (int i = 0; i < NLAYER; i++) { sc[i] = __expf(sc[i] - mx); ssum += sc[i]; }
    float inv = 1.0f / ssum;

    int d = tid * 4;
    f32x4 r; r[0] = 0.f; r[1] = 0.f; r[2] = 0.f; r[3] = 0.f;
    f32x4 h4;
#pragma unroll
    for (int lp = 0; lp < NLAYER; lp++) {
        if (lp < nl) {
            f32x4 v4 = *(const f32x4*)(hist + (size_t)lp * BT * DIM + (size_t)bt * DIM + d);
            float a = sc[lp] * inv;
            r[0] += a * v4[0]; r[1] += a * v4[1]; r[2] += a * v4[2]; r[3] += a * v4[3];
            h4 = v4;                        // last executed lp == nl-1 is h
        }
    }
    f32x4 b24 = *(const f32x4*)(b2 + d);
    f32x4 ro; ro[0] = r[0] + b24[0]; ro[1] = r[1] + b24[1]; ro[2] = r[2] + b24[2]; ro[3] = r[3] + b24[3];
    *(f32x4*)(hnext + (size_t)bt * DIM + d) = ro;

    float s1 = h4[0] + h4[1] + h4[2] + h4[3];
    float s2 = h4[0]*h4[0] + h4[1]*h4[1] + h4[2]*h4[2] + h4[3]*h4[3];
#pragma unroll
    for (int off = 32; off; off >>= 1) {
        s1 += __shfl_xor(s1, off);
        s2 += __shfl_xor(s2, off);
    }
    int w = tid >> 6, lane = tid & 63;
    if (lane == 0) { red1[w] = s1; red2[w] = s2; }
    __syncthreads();
    s1 = red1[0] + red1[1] + red1[2] + red1[3];
    s2 = red2[0] + red2[1] + red2[2] + red2[3];
    float mu = s1 * (1.0f / DIM);
    float rs = rsqrtf(s2 * (1.0f / DIM) - mu * mu + EPS_LN);

    f32x4 g4 = *(const f32x4*)(g + d);
    f32x4 b4 = *(const f32x4*)(bvec + d);
    bf16x4 uo;
#pragma unroll
    for (int c = 0; c < 4; c++) uo[c] = (__bf16)((h4[c] - mu) * rs * g4[c] + b4[c]);
    *(bf16x4*)(u + (size_t)bt * DIM + d) = uo;
}

// ----------------------------------------- weight transpose f32 -> bf16 ----
// z=0: W1 (DIM x EDIM) -> W1t (EDIM x DIM); z=1: W2 (EDIM x DIM) -> W2t (DIM x EDIM)
__global__ __launch_bounds__(256) void wtrans_kernel(
    const float* __restrict__ W1, const float* __restrict__ W2,
    __bf16* __restrict__ W1t, __bf16* __restrict__ W2t)
{
    __shared__ float t[64][65];
    int z = blockIdx.z;
    const float* src; __bf16* dst; int R, C, rt, ct;
    if (z == 0) { src = W1; dst = W1t; R = DIM;  C = EDIM; rt = blockIdx.y; ct = blockIdx.x; }
    else        { src = W2; dst = W2t; R = EDIM; C = DIM;  rt = blockIdx.x; ct = blockIdx.y; }

    int tid = threadIdx.x;
    int lr = tid >> 2, cs = (tid & 3) << 4;
    const float* sp = src + (size_t)(rt * 64 + lr) * C + ct * 64 + cs;
#pragma unroll
    for (int s = 0; s < 4; s++) {
        f32x4 v = *(const f32x4*)(sp + s * 4);
        t[lr][cs + s * 4 + 0] = v[0];
        t[lr][cs + s * 4 + 1] = v[1];
        t[lr][cs + s * 4 + 2] = v[2];
        t[lr][cs + s * 4 + 3] = v[3];
    }
    __syncthreads();
    int oc = tid >> 2, rs = (tid & 3) << 4;
    bf16x8 o0, o1;
#pragma unroll
    for (int e = 0; e < 8; e++) o0[e] = (__bf16)t[rs + e][oc];
#pragma unroll
    for (int e = 0; e < 8; e++) o1[e] = (__bf16)t[rs + 8 + e][oc];
    __bf16* dp = dst + (size_t)(ct * 64 + oc) * R + rt * 64 + rs;
    *(bf16x8*)dp = o0;
    *(bf16x8*)(dp + 8) = o1;
}

// ------------------------------------------------------------------ GEMM ---
// C = A(bf16 MxK, row stride As) * Bt(bf16 NxK, row stride Bs)^T
// m97 structure: 128x128 tile, BK=64, global_load_lds(16B) for both operands,
// XOR-swizzled source so ds_read_b128 frag reads are conflict-free.
// EPI==0: out bf16 = gelu(acc + bias), row stride N
// EPI==2: out f32 partial (split-K chunk blockIdx.z) = acc
template <int EPI>
__global__ __launch_bounds__(256, 2)
void gemm_bt(const __bf16* __restrict__ A, const __bf16* __restrict__ Bt,
             const float* __restrict__ bias, float* __restrict__ outp,
             int M, int N, int As, int Bs, int klen)
{
    __shared__ char Abuf[16384];
    __shared__ char Bbuf[16384];
    const int tid = threadIdx.x, lane = tid & 63, w = tid >> 6;
    const int wr = w >> 1, wc = w & 1;
    const int m0 = blockIdx.y * 128, n0 = blockIdx.x * 128;
    const int kbase = blockIdx.z * klen;

    f32x4 acc[4][4];
#pragma unroll
    for (int i = 0; i < 4; i++)
#pragma unroll
        for (int j = 0; j < 4; j++) { acc[i][j][0]=0.f; acc[i][j][1]=0.f; acc[i][j][2]=0.f; acc[i][j][3]=0.f; }

    const int rsub = lane >> 3;                       // row within 8-row chunk
    const int ksrc = ((lane & 7) << 4) ^ (rsub << 4); // pre-swizzled source k-byte
    const char* Ac = (const char*)A;
    const char* Bc = (const char*)Bt;
    size_t aoff[4], boff[4];
#pragma unroll
    for (int c = 0; c < 4; c++) {
        int r = w * 32 + c * 8 + rsub;
        aoff[c] = ((size_t)(m0 + r) * As + kbase) * 2 + ksrc;
        boff[c] = ((size_t)(n0 + r) * Bs + kbase) * 2 + ksrc;
    }
    const int lr = lane & 15;
    const int hib = (lane >> 4) << 4;                 // k-half byte within 32-elem group

    for (int kt = 0; kt < klen; kt += 64) {
#pragma unroll
        for (int c = 0; c < 4; c++) {
            gl_lds16(Ac + aoff[c] + (size_t)kt * 2, (void*)(Abuf + (w * 4 + c) * 1024));
            gl_lds16(Bc + boff[c] + (size_t)kt * 2, (void*)(Bbuf + (w * 4 + c) * 1024));
        }
        __syncthreads();
#pragma unroll
        for (int kk = 0; kk < 2; kk++) {
            bf16x8 af[4], bfr[4];
#pragma unroll
            for (int i = 0; i < 4; i++) {
                int row = wr * 64 + i * 16 + lr;
                af[i] = *(const bf16x8*)(Abuf + row * 128 + ((kk * 64 + hib) ^ ((row & 7) << 4)));
            }
#pragma unroll
            for (int j = 0; j < 4; j++) {
                int row = wc * 64 + j * 16 + lr;
                bfr[j] = *(const bf16x8*)(Bbuf + row * 128 + ((kk * 64 + hib) ^ ((row & 7) << 4)));
            }
#pragma unroll
            for (int i = 0; i < 4; i++)
#pragma unroll
                for (int j = 0; j < 4; j++)
                    acc[i][j] = __builtin_amdgcn_mfma_f32_16x16x32_bf16(af[i], bfr[j], acc[i][j], 0, 0, 0);
        }
        __syncthreads();
    }

    // ---- epilogue ----
    const int lrow = (lane >> 4) << 2;
    if (EPI == 0) {
        __bf16* out = (__bf16*)outp;
#pragma unroll
        for (int i = 0; i < 4; i++) {
#pragma unroll
            for (int j = 0; j < 4; j++) {
                int colg = n0 + wc * 64 + j * 16 + lr;
                float bc = bias[colg];
#pragma unroll
                for (int r = 0; r < 4; r++) {
                    int rowg = m0 + wr * 64 + i * 16 + lrow + r;
                    float v = acc[i][j][r] + bc;
                    float tt = 0.7978845608f * (v + 0.044715f * v * v * v);
                    float e = __expf(2.0f * tt);
                    float th = 1.0f - 2.0f / (e + 1.0f);
                    out[(size_t)rowg * N + colg] = (__bf16)(0.5f * v * (1.0f + th));
                }
            }
        }
    } else {
        float* out = outp + (size_t)blockIdx.z * M * N;
#pragma unroll
        for (int i = 0; i < 4; i++) {
#pragma unroll
            for (int j = 0; j < 4; j++) {
                int colg = n0 + wc * 64 + j * 16 + lr;
#pragma unroll
                for (int r = 0; r < 4; r++) {
                    int rowg = m0 + wr * 64 + i * 16 + lrow + r;
                    out[(size_t)rowg * N + colg] = acc[i][j][r];
                }
            }
        }
    }
}

// ---------------------------------------------- split-K reduce into hnext --
__global__ void reduce_kernel(const float* __restrict__ part, float* __restrict__ h)
{
    size_t i = ((size_t)blockIdx.x * 256 + threadIdx.x) * 4;
    f32x4 r = *(const f32x4*)(h + i);
#pragma unroll
    for (int z = 0; z < 4; z++) {
        f32x4 p = *(const f32x4*)(part + (size_t)z * BT * DIM + i);
        r[0] += p[0]; r[1] += p[1]; r[2] += p[2]; r[3] += p[3];
    }
    *(f32x4*)(h + i) = r;
}

// ---------------------------------------------------------------- launch ---
extern "C" void kernel_launch(void* const* d_in, const int* in_sizes, int n_in,
                              void* d_out, int out_size, void* d_ws, size_t ws_size,
                              hipStream_t stream)
{
    const float* x   = (const float*)d_in[0];
    const float* q   = (const float*)d_in[1];
    const float* kng = (const float*)d_in[2];
    const float* knb = (const float*)d_in[3];
    const float* lng = (const float*)d_in[4];
    const float* lnb = (const float*)d_in[5];
    const float* W1  = (const float*)d_in[6];
    const float* b1  = (const float*)d_in[7];
    const float* W2  = (const float*)d_in[8];
    const float* b2  = (const float*)d_in[9];

    char* ws = (char*)d_ws;
    const size_t slot = (size_t)BT * DIM;
    float*  hist    = (float*)(ws);                  // 13 * 8 MB = 109,051,904
    float*  scoresb = (float*)(ws + 109051904);      // 106,496
    __bf16* ubuf    = (__bf16*)(ws + 109158400);     // 4,194,304
    __bf16* hmid    = (__bf16*)(ws + 113352704);     // 16,777,216
    __bf16* W1t     = (__bf16*)(ws + 130129920);     // 8,388,608
    __bf16* W2t     = (__bf16*)(ws + 138518528);     // 8,388,608
    float*  part    = (float*)(ws + 146907136);      // 33,554,432 (end 180,461,568)

    hipMemcpyAsync(hist, x, slot * sizeof(float), hipMemcpyDeviceToDevice, stream);

    for (int l = 0; l < NLAYER; l++) {
        int nl = l + 1;
        int nrows = nl * BT;
        wtrans_kernel<<<dim3(64, 16, 2), 256, 0, stream>>>(
            W1 + (size_t)l * DIM * EDIM, W2 + (size_t)l * EDIM * DIM, W1t, W2t);
        scores_kernel<<<dim3((nrows + 3) / 4), 256, 0, stream>>>(
            hist, q + (size_t)l * DIM, kng + (size_t)l * DIM, knb + (size_t)l * DIM,
            scoresb, nrows);
        mix_ln_kernel<<<dim3(BT), 256, 0, stream>>>(
            hist, scoresb, lng + (size_t)l * DIM, lnb + (size_t)l * DIM,
            b2 + (size_t)l * DIM, hist + (size_t)(l + 1) * slot, ubuf, nl);
        gemm_bt<0><<<dim3(EDIM / 128, BT / 128), 256, 0, stream>>>(
            ubuf, W1t, b1 + (size_t)l * EDIM, (float*)hmid, BT, EDIM, DIM, DIM, DIM);
        gemm_bt<2><<<dim3(DIM / 128, BT / 128, 4), 256, 0, stream>>>(
            hmid, W2t, nullptr, part, BT, DIM, EDIM, EDIM, 1024);
        reduce_kernel<<<dim3(BT * DIM / 1024), 256, 0, stream>>>(
            part, hist + (size_t)(l + 1) * slot);
    }

    hipMemcpyAsync(d_out, hist + (size_t)NLAYER * slot, slot * sizeof(float),
                   hipMemcpyDeviceToDevice, stream);
}

// Round 3
// 1049.526 us; speedup vs baseline: 2.5390x; 1.0720x over previous
//
#include <hip/hip_runtime.h>
#include <math.h>

#define BATCH 2
#define TSEQ 1024
#define DIM 1024
#define NLAYER 12
#define EDIM 4096
#define BT 2048
#define EPS_LN 1e-5f

typedef __attribute__((ext_vector_type(4))) float  f32x4;
typedef __attribute__((ext_vector_type(8))) __bf16 bf16x8;
typedef __attribute__((ext_vector_type(4))) __bf16 bf16x4;

__device__ __forceinline__ void gl_lds16(const void* gptr, void* lptr) {
    __builtin_amdgcn_global_load_lds(
        (const __attribute__((address_space(1))) void*)gptr,
        (__attribute__((address_space(3))) void*)lptr,
        16, 0, 0);
}

// ------------------------------------------- fused attention per bt row ----
// One block per bt. Wave w owns history rows lp = w, w+4, w+8:
//   loads row (full 1024d across 64 lanes), stores to LDS, wave-reduces
//   LN stats + q.K score. Then softmax over nl scores, residual mix from
//   LDS, LN(h) -> u (bf16), hnext = resid + b2.
__global__ __launch_bounds__(256)
void attn_kernel(const float* __restrict__ x,
                 const float* __restrict__ hist,
                 const float* __restrict__ q,
                 const float* __restrict__ kng,
                 const float* __restrict__ knb,
                 const float* __restrict__ lng,
                 const float* __restrict__ lnb,
                 const float* __restrict__ b2,
                 float* __restrict__ hnext,
                 __bf16* __restrict__ u,
                 int nl)
{
    __shared__ float V[NLAYER][DIM];          // 48 KB
    __shared__ float sS[NLAYER], sMu[NLAYER], sRs[NLAYER];

    const int bt = blockIdx.x;
    const int tid = threadIdx.x, lane = tid & 63, w = tid >> 6;

    // per-lane g*q fragments (chunk i covers d = i*256 + lane*4)
    f32x4 gqv[4];
    float sg = 0.f, sb = 0.f;
#pragma unroll
    for (int i = 0; i < 4; i++) {
        int d = i * 256 + lane * 4;
        f32x4 g4 = *(const f32x4*)(kng + d);
        f32x4 q4 = *(const f32x4*)(q + d);
        f32x4 b4 = *(const f32x4*)(knb + d);
#pragma unroll
        for (int c = 0; c < 4; c++) {
            float gq = g4[c] * q4[c];
            gqv[i][c] = gq;
            sg += gq;
            sb += b4[c] * q4[c];
        }
    }
#pragma unroll
    for (int off = 32; off; off >>= 1) {
        sg += __shfl_xor(sg, off);
        sb += __shfl_xor(sb, off);
    }

    for (int lp = w; lp < nl; lp += 4) {
        const float* vp = (lp == 0) ? (x + (size_t)bt * DIM)
                                    : (hist + ((size_t)lp * BT + bt) * DIM);
        f32x4 vv[4];
#pragma unroll
        for (int i = 0; i < 4; i++) vv[i] = *(const f32x4*)(vp + i * 256 + lane * 4);
        float s1 = 0.f, s2 = 0.f, sq = 0.f;
#pragma unroll
        for (int i = 0; i < 4; i++) {
            *(f32x4*)(&V[lp][i * 256 + lane * 4]) = vv[i];
#pragma unroll
            for (int c = 0; c < 4; c++) {
                float xv = vv[i][c];
                s1 += xv; s2 += xv * xv; sq += xv * gqv[i][c];
            }
        }
#pragma unroll
        for (int off = 32; off; off >>= 1) {
            s1 += __shfl_xor(s1, off);
            s2 += __shfl_xor(s2, off);
            sq += __shfl_xor(sq, off);
        }
        if (lane == 0) {
            float mu = s1 * (1.0f / DIM);
            float var = s2 * (1.0f / DIM) - mu * mu;
            float rs = rsqrtf(var + EPS_LN);
            sMu[lp] = mu; sRs[lp] = rs;
            sS[lp] = (rs * (sq - mu * sg) + sb) * (1.0f / 32.0f);
        }
    }
    __syncthreads();

    // softmax over history axis (redundant per thread; static indexing only)
    float mx = -1e30f;
#pragma unroll
    for (int i = 0; i < NLAYER; i++) if (i < nl) mx = fmaxf(mx, sS[i]);
    float al[NLAYER];
    float ssum = 0.f;
#pragma unroll
    for (int i = 0; i < NLAYER; i++) {
        al[i] = (i < nl) ? __expf(sS[i] - mx) : 0.f;
        ssum += al[i];
    }
    float inv = 1.0f / ssum;

    const int d = tid * 4;
    f32x4 r; r[0] = 0.f; r[1] = 0.f; r[2] = 0.f; r[3] = 0.f;
#pragma unroll
    for (int i = 0; i < NLAYER; i++) {
        if (i < nl) {
            f32x4 v4 = *(const f32x4*)(&V[i][d]);
            float a = al[i] * inv;
            r[0] += a * v4[0]; r[1] += a * v4[1]; r[2] += a * v4[2]; r[3] += a * v4[3];
        }
    }
    f32x4 h4 = *(const f32x4*)(&V[nl - 1][d]);
    f32x4 b24 = *(const f32x4*)(b2 + d);
    f32x4 ro; ro[0] = r[0] + b24[0]; ro[1] = r[1] + b24[1];
    ro[2] = r[2] + b24[2]; ro[3] = r[3] + b24[3];
    *(f32x4*)(hnext + (size_t)bt * DIM + d) = ro;

    float mu = sMu[nl - 1], rs = sRs[nl - 1];
    f32x4 g4 = *(const f32x4*)(lng + d);
    f32x4 b4 = *(const f32x4*)(lnb + d);
    bf16x4 uo;
#pragma unroll
    for (int c = 0; c < 4; c++) uo[c] = (__bf16)((h4[c] - mu) * rs * g4[c] + b4[c]);
    *(bf16x4*)(u + (size_t)bt * DIM + d) = uo;
}

// ----------------------------------------- weight transpose f32 -> bf16 ----
__global__ __launch_bounds__(256) void wtrans_kernel(
    const float* __restrict__ W1, const float* __restrict__ W2,
    __bf16* __restrict__ W1t, __bf16* __restrict__ W2t)
{
    __shared__ float t[64][65];
    int z = blockIdx.z;
    const float* src; __bf16* dst; int R, C, rt, ct;
    if (z == 0) { src = W1; dst = W1t; R = DIM;  C = EDIM; rt = blockIdx.y; ct = blockIdx.x; }
    else        { src = W2; dst = W2t; R = EDIM; C = DIM;  rt = blockIdx.x; ct = blockIdx.y; }

    int tid = threadIdx.x;
    int lr = tid >> 2, cs = (tid & 3) << 4;
    const float* sp = src + (size_t)(rt * 64 + lr) * C + ct * 64 + cs;
#pragma unroll
    for (int s = 0; s < 4; s++) {
        f32x4 v = *(const f32x4*)(sp + s * 4);
        t[lr][cs + s * 4 + 0] = v[0];
        t[lr][cs + s * 4 + 1] = v[1];
        t[lr][cs + s * 4 + 2] = v[2];
        t[lr][cs + s * 4 + 3] = v[3];
    }
    __syncthreads();
    int oc = tid >> 2, rs = (tid & 3) << 4;
    bf16x8 o0, o1;
#pragma unroll
    for (int e = 0; e < 8; e++) o0[e] = (__bf16)t[rs + e][oc];
#pragma unroll
    for (int e = 0; e < 8; e++) o1[e] = (__bf16)t[rs + 8 + e][oc];
    __bf16* dp = dst + (size_t)(ct * 64 + oc) * R + rt * 64 + rs;
    *(bf16x8*)dp = o0;
    *(bf16x8*)(dp + 8) = o1;
}

// ------------------------------------------------------------------ GEMM ---
// C = A(bf16 MxK) * Bt(bf16 NxK)^T, m97 structure: 128x128 tile, BK=64,
// global_load_lds(16B) both operands, XOR-swizzled source addressing.
// EPI==0: out bf16 = gelu(acc + bias); EPI==2: f32 split-K partial.
template <int EPI>
__global__ __launch_bounds__(256, 3)
void gemm_bt(const __bf16* __restrict__ A, const __bf16* __restrict__ Bt,
             const float* __restrict__ bias, float* __restrict__ outp,
             int M, int N, int As, int Bs, int klen)
{
    __shared__ char Abuf[16384];
    __shared__ char Bbuf[16384];
    const int tid = threadIdx.x, lane = tid & 63, w = tid >> 6;
    const int wr = w >> 1, wc = w & 1;

    // bijective XCD swizzle over the (x,y) grid (grid count % 8 == 0)
    const int nb2 = gridDim.x * gridDim.y;
    const int fid = blockIdx.y * gridDim.x + blockIdx.x;
    const int cpx = nb2 >> 3;
    const int swz = (fid & 7) * cpx + (fid >> 3);
    const int m0 = (swz / gridDim.x) * 128;
    const int n0 = (swz % gridDim.x) * 128;
    const int kbase = blockIdx.z * klen;

    f32x4 acc[4][4];
#pragma unroll
    for (int i = 0; i < 4; i++)
#pragma unroll
        for (int j = 0; j < 4; j++) { acc[i][j][0]=0.f; acc[i][j][1]=0.f; acc[i][j][2]=0.f; acc[i][j][3]=0.f; }

    const int rsub = lane >> 3;
    const int ksrc = ((lane & 7) << 4) ^ (rsub << 4);
    const char* Ac = (const char*)A;
    const char* Bc = (const char*)Bt;
    size_t aoff[4], boff[4];
#pragma unroll
    for (int c = 0; c < 4; c++) {
        int r = w * 32 + c * 8 + rsub;
        aoff[c] = ((size_t)(m0 + r) * As + kbase) * 2 + ksrc;
        boff[c] = ((size_t)(n0 + r) * Bs + kbase) * 2 + ksrc;
    }
    const int lr = lane & 15;
    const int hib = (lane >> 4) << 4;

    for (int kt = 0; kt < klen; kt += 64) {
#pragma unroll
        for (int c = 0; c < 4; c++) {
            gl_lds16(Ac + aoff[c] + (size_t)kt * 2, (void*)(Abuf + (w * 4 + c) * 1024));
            gl_lds16(Bc + boff[c] + (size_t)kt * 2, (void*)(Bbuf + (w * 4 + c) * 1024));
        }
        __syncthreads();
#pragma unroll
        for (int kk = 0; kk < 2; kk++) {
            bf16x8 af[4], bfr[4];
#pragma unroll
            for (int i = 0; i < 4; i++) {
                int row = wr * 64 + i * 16 + lr;
                af[i] = *(const bf16x8*)(Abuf + row * 128 + ((kk * 64 + hib) ^ ((row & 7) << 4)));
            }
#pragma unroll
            for (int j = 0; j < 4; j++) {
                int row = wc * 64 + j * 16 + lr;
                bfr[j] = *(const bf16x8*)(Bbuf + row * 128 + ((kk * 64 + hib) ^ ((row & 7) << 4)));
            }
#pragma unroll
            for (int i = 0; i < 4; i++)
#pragma unroll
                for (int j = 0; j < 4; j++)
                    acc[i][j] = __builtin_amdgcn_mfma_f32_16x16x32_bf16(af[i], bfr[j], acc[i][j], 0, 0, 0);
        }
        __syncthreads();
    }

    const int lrow = (lane >> 4) << 2;
    if (EPI == 0) {
        __bf16* out = (__bf16*)outp;
#pragma unroll
        for (int i = 0; i < 4; i++) {
#pragma unroll
            for (int j = 0; j < 4; j++) {
                int colg = n0 + wc * 64 + j * 16 + lr;
                float bc = bias[colg];
#pragma unroll
                for (int r = 0; r < 4; r++) {
                    int rowg = m0 + wr * 64 + i * 16 + lrow + r;
                    float v = acc[i][j][r] + bc;
                    float tt = 0.7978845608f * (v + 0.044715f * v * v * v);
                    float e = __expf(2.0f * tt);
                    float th = 1.0f - 2.0f / (e + 1.0f);
                    out[(size_t)rowg * N + colg] = (__bf16)(0.5f * v * (1.0f + th));
                }
            }
        }
    } else {
        float* out = outp + (size_t)blockIdx.z * M * N;
#pragma unroll
        for (int i = 0; i < 4; i++) {
#pragma unroll
            for (int j = 0; j < 4; j++) {
                int colg = n0 + wc * 64 + j * 16 + lr;
#pragma unroll
                for (int r = 0; r < 4; r++) {
                    int rowg = m0 + wr * 64 + i * 16 + lrow + r;
                    out[(size_t)rowg * N + colg] = acc[i][j][r];
                }
            }
        }
    }
}

// ---------------------------------------------- split-K reduce into hnext --
__global__ void reduce_kernel(const float* __restrict__ part, float* __restrict__ h)
{
    size_t i = ((size_t)blockIdx.x * 256 + threadIdx.x) * 4;
    f32x4 r = *(const f32x4*)(h + i);
#pragma unroll
    for (int z = 0; z < 4; z++) {
        f32x4 p = *(const f32x4*)(part + (size_t)z * BT * DIM + i);
        r[0] += p[0]; r[1] += p[1]; r[2] += p[2]; r[3] += p[3];
    }
    *(f32x4*)(h + i) = r;
}

// ---------------------------------------------------------------- launch ---
extern "C" void kernel_launch(void* const* d_in, const int* in_sizes, int n_in,
                              void* d_out, int out_size, void* d_ws, size_t ws_size,
                              hipStream_t stream)
{
    const float* x   = (const float*)d_in[0];
    const float* q   = (const float*)d_in[1];
    const float* kng = (const float*)d_in[2];
    const float* knb = (const float*)d_in[3];
    const float* lng = (const float*)d_in[4];
    const float* lnb = (const float*)d_in[5];
    const float* W1  = (const float*)d_in[6];
    const float* b1  = (const float*)d_in[7];
    const float* W2  = (const float*)d_in[8];
    const float* b2  = (const float*)d_in[9];

    char* ws = (char*)d_ws;
    const size_t slot = (size_t)BT * DIM;
    float*  hist    = (float*)(ws);                  // slots 1..12 used (96 MB span)
    __bf16* ubuf    = (__bf16*)(ws + 109051904);     // 4 MB
    __bf16* hmid    = (__bf16*)(ws + 113246208);     // 16 MB
    __bf16* W1t     = (__bf16*)(ws + 130023424);     // 8 MB
    __bf16* W2t     = (__bf16*)(ws + 138412032);     // 8 MB
    float*  part    = (float*)(ws + 146800640);      // 32 MB (end ~180 MB)

    for (int l = 0; l < NLAYER; l++) {
        int nl = l + 1;
        wtrans_kernel<<<dim3(64, 16, 2), 256, 0, stream>>>(
            W1 + (size_t)l * DIM * EDIM, W2 + (size_t)l * EDIM * DIM, W1t, W2t);
        attn_kernel<<<dim3(BT), 256, 0, stream>>>(
            x, hist, q + (size_t)l * DIM,
            kng + (size_t)l * DIM, knb + (size_t)l * DIM,
            lng + (size_t)l * DIM, lnb + (size_t)l * DIM,
            b2 + (size_t)l * DIM,
            hist + (size_t)nl * slot, ubuf, nl);
        gemm_bt<0><<<dim3(EDIM / 128, BT / 128), 256, 0, stream>>>(
            ubuf, W1t, b1 + (size_t)l * EDIM, (float*)hmid, BT, EDIM, DIM, DIM, DIM);
        gemm_bt<2><<<dim3(DIM / 128, BT / 128, 4), 256, 0, stream>>>(
            hmid, W2t, nullptr, part, BT, DIM, EDIM, EDIM, 1024);
        reduce_kernel<<<dim3(BT * DIM / 1024), 256, 0, stream>>>(
            part, hist + (size_t)nl * slot);
    }

    hipMemcpyAsync(d_out, hist + (size_t)NLAYER * slot, slot * sizeof(float),
                   hipMemcpyDeviceToDevice, stream);
}

// Round 4
// 1028.450 us; speedup vs baseline: 2.5910x; 1.0205x over previous
//
#include <hip/hip_runtime.h>
#include <math.h>

#define BATCH 2
#define TSEQ 1024
#define DIM 1024
#define NLAYER 12
#define EDIM 4096
#define BT 2048
#define EPS_LN 1e-5f

typedef __attribute__((ext_vector_type(4))) float  f32x4;
typedef __attribute__((ext_vector_type(8))) __bf16 bf16x8;
typedef __attribute__((ext_vector_type(4))) __bf16 bf16x4;

__device__ __forceinline__ void gl_lds16(const void* gptr, void* lptr) {
    __builtin_amdgcn_global_load_lds(
        (const __attribute__((address_space(1))) void*)gptr,
        (__attribute__((address_space(3))) void*)lptr,
        16, 0, 0);
}

// ------------------------------------------- fused attention per bt row ----
__global__ __launch_bounds__(256)
void attn_kernel(const float* __restrict__ x,
                 const float* __restrict__ hist,
                 const float* __restrict__ q,
                 const float* __restrict__ kng,
                 const float* __restrict__ knb,
                 const float* __restrict__ lng,
                 const float* __restrict__ lnb,
                 const float* __restrict__ b2,
                 float* __restrict__ hnext,
                 __bf16* __restrict__ u,
                 int nl)
{
    __shared__ float V[NLAYER][DIM];          // 48 KB
    __shared__ float sS[NLAYER], sMu[NLAYER], sRs[NLAYER];

    const int bt = blockIdx.x;
    const int tid = threadIdx.x, lane = tid & 63, w = tid >> 6;

    f32x4 gqv[4];
    float sg = 0.f, sb = 0.f;
#pragma unroll
    for (int i = 0; i < 4; i++) {
        int d = i * 256 + lane * 4;
        f32x4 g4 = *(const f32x4*)(kng + d);
        f32x4 q4 = *(const f32x4*)(q + d);
        f32x4 b4 = *(const f32x4*)(knb + d);
#pragma unroll
        for (int c = 0; c < 4; c++) {
            float gq = g4[c] * q4[c];
            gqv[i][c] = gq;
            sg += gq;
            sb += b4[c] * q4[c];
        }
    }
#pragma unroll
    for (int off = 32; off; off >>= 1) {
        sg += __shfl_xor(sg, off);
        sb += __shfl_xor(sb, off);
    }

    for (int lp = w; lp < nl; lp += 4) {
        const float* vp = (lp == 0) ? (x + (size_t)bt * DIM)
                                    : (hist + ((size_t)lp * BT + bt) * DIM);
        f32x4 vv[4];
#pragma unroll
        for (int i = 0; i < 4; i++) vv[i] = *(const f32x4*)(vp + i * 256 + lane * 4);
        float s1 = 0.f, s2 = 0.f, sq = 0.f;
#pragma unroll
        for (int i = 0; i < 4; i++) {
            *(f32x4*)(&V[lp][i * 256 + lane * 4]) = vv[i];
#pragma unroll
            for (int c = 0; c < 4; c++) {
                float xv = vv[i][c];
                s1 += xv; s2 += xv * xv; sq += xv * gqv[i][c];
            }
        }
#pragma unroll
        for (int off = 32; off; off >>= 1) {
            s1 += __shfl_xor(s1, off);
            s2 += __shfl_xor(s2, off);
            sq += __shfl_xor(sq, off);
        }
        if (lane == 0) {
            float mu = s1 * (1.0f / DIM);
            float var = s2 * (1.0f / DIM) - mu * mu;
            float rs = rsqrtf(var + EPS_LN);
            sMu[lp] = mu; sRs[lp] = rs;
            sS[lp] = (rs * (sq - mu * sg) + sb) * (1.0f / 32.0f);
        }
    }
    __syncthreads();

    float mx = -1e30f;
#pragma unroll
    for (int i = 0; i < NLAYER; i++) if (i < nl) mx = fmaxf(mx, sS[i]);
    float al[NLAYER];
    float ssum = 0.f;
#pragma unroll
    for (int i = 0; i < NLAYER; i++) {
        al[i] = (i < nl) ? __expf(sS[i] - mx) : 0.f;
        ssum += al[i];
    }
    float inv = 1.0f / ssum;

    const int d = tid * 4;
    f32x4 r; r[0] = 0.f; r[1] = 0.f; r[2] = 0.f; r[3] = 0.f;
#pragma unroll
    for (int i = 0; i < NLAYER; i++) {
        if (i < nl) {
            f32x4 v4 = *(const f32x4*)(&V[i][d]);
            float a = al[i] * inv;
            r[0] += a * v4[0]; r[1] += a * v4[1]; r[2] += a * v4[2]; r[3] += a * v4[3];
        }
    }
    f32x4 h4 = *(const f32x4*)(&V[nl - 1][d]);
    f32x4 b24 = *(const f32x4*)(b2 + d);
    f32x4 ro; ro[0] = r[0] + b24[0]; ro[1] = r[1] + b24[1];
    ro[2] = r[2] + b24[2]; ro[3] = r[3] + b24[3];
    *(f32x4*)(hnext + (size_t)bt * DIM + d) = ro;

    float mu = sMu[nl - 1], rs = sRs[nl - 1];
    f32x4 g4 = *(const f32x4*)(lng + d);
    f32x4 b4 = *(const f32x4*)(lnb + d);
    bf16x4 uo;
#pragma unroll
    for (int c = 0; c < 4; c++) uo[c] = (__bf16)((h4[c] - mu) * rs * g4[c] + b4[c]);
    *(bf16x4*)(u + (size_t)bt * DIM + d) = uo;
}

// ----------------------------------------- weight transpose f32 -> bf16 ----
__global__ __launch_bounds__(256) void wtrans_kernel(
    const float* __restrict__ W1, const float* __restrict__ W2,
    __bf16* __restrict__ W1t, __bf16* __restrict__ W2t)
{
    __shared__ float t[64][65];
    int z = blockIdx.z;
    const float* src; __bf16* dst; int R, C, rt, ct;
    if (z == 0) { src = W1; dst = W1t; R = DIM;  C = EDIM; rt = blockIdx.y; ct = blockIdx.x; }
    else        { src = W2; dst = W2t; R = EDIM; C = DIM;  rt = blockIdx.x; ct = blockIdx.y; }

    int tid = threadIdx.x;
    int lr = tid >> 2, cs = (tid & 3) << 4;
    const float* sp = src + (size_t)(rt * 64 + lr) * C + ct * 64 + cs;
#pragma unroll
    for (int s = 0; s < 4; s++) {
        f32x4 v = *(const f32x4*)(sp + s * 4);
        t[lr][cs + s * 4 + 0] = v[0];
        t[lr][cs + s * 4 + 1] = v[1];
        t[lr][cs + s * 4 + 2] = v[2];
        t[lr][cs + s * 4 + 3] = v[3];
    }
    __syncthreads();
    int oc = tid >> 2, rs = (tid & 3) << 4;
    bf16x8 o0, o1;
#pragma unroll
    for (int e = 0; e < 8; e++) o0[e] = (__bf16)t[rs + e][oc];
#pragma unroll
    for (int e = 0; e < 8; e++) o1[e] = (__bf16)t[rs + 8 + e][oc];
    __bf16* dp = dst + (size_t)(ct * 64 + oc) * R + rt * 64 + rs;
    *(bf16x8*)dp = o0;
    *(bf16x8*)(dp + 8) = o1;
}

// ------------------------------------------------------------------ GEMM ---
// C = A(bf16 MxK) * Bt(bf16 NxK)^T.  128x256 tile, 8 waves (64x64 each),
// BK=64, triple-buffered LDS, prefetch depth 2, counted vmcnt(6) before a
// raw s_barrier (never drains to 0 in steady state), setprio around MFMA.
// K per block is fixed at 1024 (16 K-steps). EPI==0: bf16 gelu(acc+bias).
// EPI==2: f32 split-K partial at slice blockIdx.y.
#define STG 49152   // A 16KB + B 32KB per stage

template <int EPI, int NTN>
__global__ __launch_bounds__(512, 1)
void gemm8(const __bf16* __restrict__ A, const __bf16* __restrict__ Bt,
           const float* __restrict__ bias, float* __restrict__ outp,
           int N, int As, int Bs)
{
    __shared__ char lds[3 * STG];          // 144 KB
    const int tid = threadIdx.x, lane = tid & 63, w = tid >> 6;
    const int wm = w >> 2, wn = w & 3;
    const int lr = lane & 15;
    const int hib = (lane >> 4) << 4;
    const int NT = 16;

    // bijective XCD swizzle (gridDim.x % 8 == 0: 256 or 64)
    const int nb = gridDim.x;
    const int fid = blockIdx.x;
    const int swz = (fid & 7) * (nb >> 3) + (fid >> 3);
    const int m0 = (swz / NTN) * 128;
    const int n0 = (swz % NTN) * 256;
    const int kbase = blockIdx.y * 1024;

    f32x4 acc[4][4];
#pragma unroll
    for (int i = 0; i < 4; i++)
#pragma unroll
        for (int j = 0; j < 4; j++) { acc[i][j][0]=0.f; acc[i][j][1]=0.f; acc[i][j][2]=0.f; acc[i][j][3]=0.f; }

    // staging: thread -> (row tid>>3 within 64-row issue, 16B k-slot tid&7),
    // source k-byte pre-XORed so linear LDS + swizzled read is conflict-free
    const int srow = tid >> 3;
    const int ksrc = ((tid & 7) << 4) ^ ((srow & 7) << 4);
    const char* Ac = (const char*)A;
    const char* Bc = (const char*)Bt;
    size_t aoff[2], boff[4];
#pragma unroll
    for (int c = 0; c < 2; c++)
        aoff[c] = ((size_t)(m0 + c * 64 + srow) * As + kbase) * 2 + ksrc;
#pragma unroll
    for (int c = 0; c < 4; c++)
        boff[c] = ((size_t)(n0 + c * 64 + srow) * Bs + kbase) * 2 + ksrc;

    char* abw = lds + w * 1024;            // wave-uniform LDS bases
    char* bbw = lds + 16384 + w * 1024;

    auto STAGE = [&](int tt, int bi) {
        size_t kb = (size_t)tt * 128;      // 64 elems * 2B
        char* ab = abw + bi * STG;
        char* bb = bbw + bi * STG;
#pragma unroll
        for (int c = 0; c < 2; c++) gl_lds16(Ac + aoff[c] + kb, ab + c * 8192);
#pragma unroll
        for (int c = 0; c < 4; c++) gl_lds16(Bc + boff[c] + kb, bb + c * 8192);
    };

    STAGE(0, 0);
    STAGE(1, 1);

    int sb = 0, st = 2;
#pragma unroll 1
    for (int t = 0; t < NT; ++t) {
        // per-wave wait for tile t's 6 loads, THEN barrier => tile t globally
        // resident; tile t+1's 6 loads stay in flight across the barrier.
        if (t < NT - 1) asm volatile("s_waitcnt vmcnt(6)" ::: "memory");
        else            asm volatile("s_waitcnt vmcnt(0)" ::: "memory");
        __builtin_amdgcn_s_barrier();
        __builtin_amdgcn_sched_barrier(0);

        if (t + 2 < NT) STAGE(t + 2, st);  // overwrites buffer everyone left at the barrier

        const char* base = lds + sb * STG;
        bf16x8 af[2][4], bfr[2][4];
#pragma unroll
        for (int kk = 0; kk < 2; kk++) {
#pragma unroll
            for (int i = 0; i < 4; i++) {
                int ra = wm * 64 + i * 16 + lr;
                af[kk][i] = *(const bf16x8*)(base + ra * 128 + ((kk * 64 + hib) ^ ((ra & 7) << 4)));
            }
#pragma unroll
            for (int j = 0; j < 4; j++) {
                int rb = wn * 64 + j * 16 + lr;
                bfr[kk][j] = *(const bf16x8*)(base + 16384 + rb * 128 + ((kk * 64 + hib) ^ ((rb & 7) << 4)));
            }
        }
        __builtin_amdgcn_s_setprio(1);
#pragma unroll
        for (int kk = 0; kk < 2; kk++)
#pragma unroll
            for (int i = 0; i < 4; i++)
#pragma unroll
                for (int j = 0; j < 4; j++)
                    acc[i][j] = __builtin_amdgcn_mfma_f32_16x16x32_bf16(af[kk][i], bfr[kk][j], acc[i][j], 0, 0, 0);
        __builtin_amdgcn_s_setprio(0);

        sb = (sb == 2) ? 0 : sb + 1;
        st = (st == 2) ? 0 : st + 1;
    }

    const int lrow = (lane >> 4) << 2;
    if (EPI == 0) {
        __bf16* out = (__bf16*)outp;
#pragma unroll
        for (int i = 0; i < 4; i++) {
#pragma unroll
            for (int j = 0; j < 4; j++) {
                int colg = n0 + wn * 64 + j * 16 + lr;
                float bc = bias[colg];
#pragma unroll
                for (int r = 0; r < 4; r++) {
                    int rowg = m0 + wm * 64 + i * 16 + lrow + r;
                    float v = acc[i][j][r] + bc;
                    float tt2 = 0.7978845608f * (v + 0.044715f * v * v * v);
                    float e = __expf(2.0f * tt2);
                    float th = 1.0f - 2.0f / (e + 1.0f);
                    out[(size_t)rowg * N + colg] = (__bf16)(0.5f * v * (1.0f + th));
                }
            }
        }
    } else {
        float* out = outp + (size_t)blockIdx.y * BT * N;
#pragma unroll
        for (int i = 0; i < 4; i++) {
#pragma unroll
            for (int j = 0; j < 4; j++) {
                int colg = n0 + wn * 64 + j * 16 + lr;
#pragma unroll
                for (int r = 0; r < 4; r++) {
                    int rowg = m0 + wm * 64 + i * 16 + lrow + r;
                    out[(size_t)rowg * N + colg] = acc[i][j][r];
                }
            }
        }
    }
}

// ---------------------------------------------- split-K reduce into hnext --
__global__ void reduce_kernel(const float* __restrict__ part, float* __restrict__ h)
{
    size_t i = ((size_t)blockIdx.x * 256 + threadIdx.x) * 4;
    f32x4 r = *(const f32x4*)(h + i);
#pragma unroll
    for (int z = 0; z < 4; z++) {
        f32x4 p = *(const f32x4*)(part + (size_t)z * BT * DIM + i);
        r[0] += p[0]; r[1] += p[1]; r[2] += p[2]; r[3] += p[3];
    }
    *(f32x4*)(h + i) = r;
}

// ---------------------------------------------------------------- launch ---
extern "C" void kernel_launch(void* const* d_in, const int* in_sizes, int n_in,
                              void* d_out, int out_size, void* d_ws, size_t ws_size,
                              hipStream_t stream)
{
    const float* x   = (const float*)d_in[0];
    const float* q   = (const float*)d_in[1];
    const float* kng = (const float*)d_in[2];
    const float* knb = (const float*)d_in[3];
    const float* lng = (const float*)d_in[4];
    const float* lnb = (const float*)d_in[5];
    const float* W1  = (const float*)d_in[6];
    const float* b1  = (const float*)d_in[7];
    const float* W2  = (const float*)d_in[8];
    const float* b2  = (const float*)d_in[9];

    char* ws = (char*)d_ws;
    const size_t slot = (size_t)BT * DIM;
    float*  hist    = (float*)(ws);                  // slots 1..12 used
    __bf16* ubuf    = (__bf16*)(ws + 109051904);     // 4 MB
    __bf16* hmid    = (__bf16*)(ws + 113246208);     // 16 MB
    __bf16* W1t     = (__bf16*)(ws + 130023424);     // 8 MB
    __bf16* W2t     = (__bf16*)(ws + 138412032);     // 8 MB
    float*  part    = (float*)(ws + 146800640);      // 32 MB (end ~180 MB)

    for (int l = 0; l < NLAYER; l++) {
        int nl = l + 1;
        wtrans_kernel<<<dim3(64, 16, 2), 256, 0, stream>>>(
            W1 + (size_t)l * DIM * EDIM, W2 + (size_t)l * EDIM * DIM, W1t, W2t);
        attn_kernel<<<dim3(BT), 256, 0, stream>>>(
            x, hist, q + (size_t)l * DIM,
            kng + (size_t)l * DIM, knb + (size_t)l * DIM,
            lng + (size_t)l * DIM, lnb + (size_t)l * DIM,
            b2 + (size_t)l * DIM,
            hist + (size_t)nl * slot, ubuf, nl);
        gemm8<0, 16><<<dim3(256, 1), 512, 0, stream>>>(
            ubuf, W1t, b1 + (size_t)l * EDIM, (float*)hmid, EDIM, DIM, DIM);
        gemm8<2, 4><<<dim3(64, 4), 512, 0, stream>>>(
            hmid, W2t, nullptr, part, DIM, EDIM, EDIM);
        reduce_kernel<<<dim3(BT * DIM / 1024), 256, 0, stream>>>(
            part, hist + (size_t)nl * slot);
    }

    hipMemcpyAsync(d_out, hist + (size_t)NLAYER * slot, slot * sizeof(float),
                   hipMemcpyDeviceToDevice, stream);
}